// Round 12
// baseline (205.262 us; speedup 1.0000x reference)
//
#include <hip/hip_runtime.h>
#include <hip/hip_bf16.h>
#include <stdint.h>

#define HH 80
#define WW 80
#define NQ 6400        // H*W
#define CD 256         // embed dim
#define BB 8
#define OUT_HALF 13107200   // B*C*H*W
#define PE_NEG 0.0719557841560639f   // ln(10000)/128

typedef __attribute__((ext_vector_type(4))) float f32x4;
typedef __bf16 bf16_t;
typedef __attribute__((ext_vector_type(8))) __bf16 bf16x8;

using gp1_t = const __attribute__((address_space(1))) void*;
using lp3_t = __attribute__((address_space(3))) void*;

__device__ __forceinline__ void gload_lds16(const void* g, void* l) {
    __builtin_amdgcn_global_load_lds((gp1_t)g, (lp3_t)l, 16, 0, 0);
}

// ---------------- weight transposes -> bf16, rows = output col, K-contig ----------------
__global__ __launch_bounds__(256) void wprep_kernel(const float* __restrict__ Wv,
                                                    const float* __restrict__ Woff,
                                                    const float* __restrict__ Wattn,
                                                    const float* __restrict__ Wout,
                                                    bf16_t* __restrict__ WvT,
                                                    bf16_t* __restrict__ WoaT,
                                                    bf16_t* __restrict__ WoT) {
    int idx = blockIdx.x * 256 + threadIdx.x;
    if (idx < 65536) {
        int cp = idx >> 8, c = idx & 255;
        WvT[idx] = (bf16_t)Wv[c * 256 + cp];
        WoT[idx] = (bf16_t)Wout[c * 256 + cp];
    }
    if (idx < 96 * 256) {
        int j = idx >> 8, c = idx & 255;
        WoaT[idx] = (bf16_t)(j < 64 ? Woff[c * 64 + j] : Wattn[c * 32 + (j - 64)]);
    }
}

// ---- GEMM1: vproj[n][c'] = (value^T)[n][:] . WvT[c'][:] + b_value[c']  (bf16 out) ----
__global__ __launch_bounds__(256, 3) void gemm_vproj(const float* __restrict__ V,   // [b][c][n] f32
                                                     const bf16_t* __restrict__ Y,  // WvT [c'][c]
                                                     const float* __restrict__ bias,
                                                     bf16_t* __restrict__ D) {
    __shared__ __align__(16) bf16_t lx[128 * 72];   // [n][k] stride 72 elems = 144 B
    __shared__ __align__(16) bf16_t ly[128 * 64];
    int b = blockIdx.x & 7;
    int nloc = (blockIdx.x >> 3) * 128;
    int m0 = b * NQ + nloc;
    int c0 = blockIdx.y * 128;
    const float* src = V + (size_t)b * CD * NQ + nloc;
    int tid = threadIdx.x, wv = tid >> 6, ln = tid & 63;
    f32x4 acc[4][4] = {};
    int wr = (wv >> 1) * 64, wc = (wv & 1) * 64;
    int nl = tid & 31;
    for (int kt = 0; kt < 4; ++kt) {
#pragma unroll
        for (int q8 = 0; q8 < 4; ++q8) {
            int q = wv * 4 + q8;
            int row = q * 8 + (ln >> 3);
            int jj = (ln & 7) ^ (row & 7);
            gload_lds16((const char*)Y + ((size_t)(c0 + row)) * 512 + (size_t)kt * 128 + jj * 16,
                        (char*)ly + q * 1024);
        }
#pragma unroll
        for (int i = 0; i < 4; ++i) {
            int kp = (tid >> 5) + i * 8;
            int k = kp * 2;
            const float* s0 = src + (size_t)(kt * 64 + k) * NQ;
#pragma unroll
            for (int l = 0; l < 4; ++l) {
                int n = nl + 32 * l;
                float v0 = s0[n];
                float v1 = s0[NQ + n];
                union { bf16_t h[2]; uint32_t u; } pk;
                pk.h[0] = (bf16_t)v0; pk.h[1] = (bf16_t)v1;
                *(uint32_t*)((char*)lx + n * 144 + k * 2) = pk.u;
            }
        }
        __syncthreads();
#pragma unroll
        for (int ks = 0; ks < 2; ++ks) {
            bf16x8 xa[4], yb[4];
#pragma unroll
            for (int i = 0; i < 4; i++) {
                int m = wr + i * 16 + (ln & 15);
                xa[i] = *(const bf16x8*)((const char*)lx + m * 144 + ks * 64 + (ln >> 4) * 16);
                int n = wc + i * 16 + (ln & 15);
                int cn = (ks * 4 + (ln >> 4)) ^ (n & 7);
                yb[i] = *(const bf16x8*)((const char*)ly + n * 128 + cn * 16);
            }
#pragma unroll
            for (int i = 0; i < 4; i++)
#pragma unroll
                for (int j = 0; j < 4; j++)
                    acc[i][j] = __builtin_amdgcn_mfma_f32_16x16x32_bf16(xa[i], yb[j], acc[i][j], 0, 0, 0);
        }
        __syncthreads();
    }
#pragma unroll
    for (int i = 0; i < 4; i++)
#pragma unroll
        for (int j = 0; j < 4; j++) {
            int col = c0 + wc + j * 16 + (ln & 15);
            float bv = bias[col];
#pragma unroll
            for (int rg = 0; rg < 4; rg++) {
                int row = m0 + wr + i * 16 + (ln >> 4) * 4 + rg;
                D[(size_t)row * 256 + col] = (bf16_t)(acc[i][j][rg] + bv);
            }
        }
}

// ==== FUSED: oa GEMM + sampling (samp in LDS) + out GEMM + epilogue ====
// grid 1600 = 8 batches (bid&7) x 200 tiles of 32 queries. 256 thr, LDS 32768 -> 5 blocks/CU.
// LDS map: R1 [0,16384): lx[32][72] (phase A) -> sampL 32x512B XOR-swizzled (B/C)
//          R2 [16384,32768): ly[96][64] (A) -> oaT[32][100] (A-epi/B) -> wx[128][64] (C)
//                            -> tile[64][36] f32 (C-epi). All overlays barrier-separated.
__global__ __launch_bounds__(256, 5) void oa_sample_out(
        const float* __restrict__ Q,     // [b][c][n] f32
        const bf16_t* __restrict__ Woa,  // WoaT [j][c]
        const float* __restrict__ boff,
        const float* __restrict__ battn,
        const bf16_t* __restrict__ vp,   // vproj [b*NQ][256]
        const bf16_t* __restrict__ WoT,  // [c'][c]
        const float* __restrict__ bout,
        const float* __restrict__ value, // [b][c][n] f32
        float* __restrict__ out) {
    __shared__ __align__(16) char smem[32768];
    char* sampL = smem;                       // 16 KB (phase B/C)
    bf16_t* lx = (bf16_t*)smem;               // [32][72] (phase A)
    bf16_t* ly = (bf16_t*)(smem + 16384);     // [96][64] (phase A)
    bf16_t* oaT = (bf16_t*)(smem + 16384);    // [32][100] (after phase A)
    bf16_t* wx = (bf16_t*)(smem + 16384);     // [128][64] (phase C)
    float* tile = (float*)(smem + 16384);     // [64][36] f32 (phase C epilogue)

    int bid = blockIdx.x;
    int b = bid & 7;
    int nloc = (bid >> 3) * 32;               // query base within batch
    int tid = threadIdx.x, wv = tid >> 6, ln = tid & 63;
    const float* src = Q + (size_t)b * CD * NQ + nloc;

    // ---------------- Phase A: oa GEMM (M=32, N=96, K=256) ----------------
    f32x4 accA[3] = {};
    int mi = wv & 1, nh3 = wv >> 1;
    for (int kt = 0; kt < 4; ++kt) {
#pragma unroll
        for (int q3 = 0; q3 < 3; ++q3) {
            int q = wv * 3 + q3;
            int row = q * 8 + (ln >> 3);
            int jj = (ln & 7) ^ (row & 7);
            gload_lds16((const char*)Woa + ((size_t)row) * 512 + (size_t)kt * 128 + jj * 16,
                        (char*)ly + q * 1024);
        }
        // A stage with inline PE (32 rows, 64 k)
        {
            int n = tid & 31;
            int p = nloc + n;
            int hh = p / WW, ww = p - hh * WW;
#pragma unroll
            for (int i = 0; i < 4; ++i) {
                int kp = (tid >> 5) + i * 8;
                int k = kp * 2;
                int c = kt * 64 + k;
                float d = __expf((float)(2 * (c >> 2)) * -PE_NEG);
                const float* s0 = src + (size_t)c * NQ;
                float pos = (c & 2) ? (float)(hh + 1) : (float)(ww + 1);
                float sv, cv;
                __sincosf(pos * d, &sv, &cv);
                float v0 = s0[n] + sv;
                float v1 = s0[NQ + n] + cv;
                union { bf16_t h2[2]; uint32_t u; } pk;
                pk.h2[0] = (bf16_t)v0; pk.h2[1] = (bf16_t)v1;
                *(uint32_t*)((char*)lx + n * 144 + k * 2) = pk.u;
            }
        }
        __syncthreads();
#pragma unroll
        for (int ks = 0; ks < 2; ++ks) {
            bf16x8 xa, yb[3];
            int m = mi * 16 + (ln & 15);
            xa = *(const bf16x8*)((const char*)lx + m * 144 + ks * 64 + (ln >> 4) * 16);
#pragma unroll
            for (int j = 0; j < 3; j++) {
                int n = (nh3 * 3 + j) * 16 + (ln & 15);
                int cn = (ks * 4 + (ln >> 4)) ^ (n & 7);
                yb[j] = *(const bf16x8*)((const char*)ly + n * 128 + cn * 16);
            }
#pragma unroll
            for (int j = 0; j < 3; j++)
                accA[j] = __builtin_amdgcn_mfma_f32_16x16x32_bf16(xa, yb[j], accA[j], 0, 0, 0);
        }
        __syncthreads();
    }
    // phase A epilogue -> oaT (overlays dead ly; after last barrier)
#pragma unroll
    for (int j = 0; j < 3; j++) {
        int col = (nh3 * 3 + j) * 16 + (ln & 15);
        float bv = col < 64 ? boff[col] : battn[col - 64];
#pragma unroll
        for (int rg = 0; rg < 4; rg++) {
            int rloc = mi * 16 + (ln >> 4) * 4 + rg;
            oaT[rloc * 100 + col] = (bf16_t)(accA[j][rg] + bv);
        }
    }
    __syncthreads();

    // ---------------- Phase B: sampling -> samp LDS (XOR-swizzled), 2 rounds ----------------
    {
        int h = (tid >> 1) & 7, sh = tid & 1;
        const bf16_t* vb = vp + (size_t)b * NQ * CD + h * 32 + sh * 16;
#pragma unroll
        for (int rnd = 0; rnd < 2; ++rnd) {
            int q = rnd * 16 + (tid >> 4);
            int n = nloc + q;
            const bf16_t* sq = oaT + q * 100;
            float l0 = (float)sq[64 + h * 4 + 0], l1 = (float)sq[64 + h * 4 + 1];
            float l2 = (float)sq[64 + h * 4 + 2], l3 = (float)sq[64 + h * 4 + 3];
            float mx = fmaxf(fmaxf(l0, l1), fmaxf(l2, l3));
            float e0 = __expf(l0 - mx), e1 = __expf(l1 - mx), e2 = __expf(l2 - mx), e3 = __expf(l3 - mx);
            float inv = 1.f / (e0 + e1 + e2 + e3);
            float aw[4] = {e0 * inv, e1 * inv, e2 * inv, e3 * inv};
            float xb = (float)(n % WW) * (80.f / 79.f) - 0.5f;
            float yb = (float)(n / WW) * (80.f / 79.f) - 0.5f;
            float wgt[16];
            int idx[16];
#pragma unroll
            for (int p = 0; p < 4; p++) {
                float x = xb + (float)sq[h * 8 + p * 2];
                float y = yb + (float)sq[h * 8 + p * 2 + 1];
                float x0f = floorf(x), y0f = floorf(y);
                float wx_ = x - x0f, wy_ = y - y0f;
                int ix = (int)x0f, iy = (int)y0f;
                bool vx0 = (unsigned)ix < (unsigned)WW, vx1 = (unsigned)(ix + 1) < (unsigned)WW;
                bool vy0 = (unsigned)iy < (unsigned)HH, vy1 = (unsigned)(iy + 1) < (unsigned)HH;
                int cx0 = min(max(ix, 0), WW - 1), cx1 = min(max(ix + 1, 0), WW - 1);
                int cy0 = min(max(iy, 0), HH - 1), cy1 = min(max(iy + 1, 0), HH - 1);
                float ap = aw[p];
                wgt[p * 4 + 0] = (vx0 && vy0) ? ap * (1.f - wx_) * (1.f - wy_) : 0.f;
                wgt[p * 4 + 1] = (vx1 && vy0) ? ap * wx_ * (1.f - wy_) : 0.f;
                wgt[p * 4 + 2] = (vx0 && vy1) ? ap * (1.f - wx_) * wy_ : 0.f;
                wgt[p * 4 + 3] = (vx1 && vy1) ? ap * wx_ * wy_ : 0.f;
                idx[p * 4 + 0] = cy0 * WW + cx0;
                idx[p * 4 + 1] = cy0 * WW + cx1;
                idx[p * 4 + 2] = cy1 * WW + cx0;
                idx[p * 4 + 3] = cy1 * WW + cx1;
            }
            float fac[16];
#pragma unroll
            for (int j = 0; j < 16; j++) fac[j] = 0.f;
#pragma unroll
            for (int pc = 0; pc < 16; ++pc) {
                const bf16x8* p8 = (const bf16x8*)(vb + (size_t)idx[pc] * CD);
                bf16x8 v0 = p8[0], v1 = p8[1];
                float w = wgt[pc];
#pragma unroll
                for (int j = 0; j < 8; j++) fac[j] += (float)v0[j] * w;
#pragma unroll
                for (int j = 0; j < 8; j++) fac[8 + j] += (float)v1[j] * w;
            }
            bf16x8 o0, o1;
#pragma unroll
            for (int j = 0; j < 8; j++) { o0[j] = (bf16_t)fac[j]; o1[j] = (bf16_t)fac[8 + j]; }
            int c0 = 4 * h + 2 * sh;          // 16B chunk index (of 32)
            *(bf16x8*)(sampL + q * 512 + ((c0 ^ (q & 7)) * 16)) = o0;
            *(bf16x8*)(sampL + q * 512 + (((c0 + 1) ^ (q & 7)) * 16)) = o1;
        }
    }
    __syncthreads();

    // ---------------- Phase C: out GEMM 256c' x 32n (2 passes of 128 c') ----------------
    const float* qp = Q + (size_t)b * CD * NQ;
    const float* vvp = value + (size_t)b * CD * NQ;
    float* o0p = out + (size_t)b * CD * NQ;
    float* o1p = out + OUT_HALF + (size_t)b * CD * NQ;
    int mg = wv >> 1, nh = wv & 1;
    for (int p = 0; p < 2; ++p) {
        int cb = p * 128;
        f32x4 acc[4];
#pragma unroll
        for (int i = 0; i < 4; i++) acc[i] = (f32x4){0.f, 0.f, 0.f, 0.f};
        for (int kt = 0; kt < 4; ++kt) {
#pragma unroll
            for (int q8 = 0; q8 < 4; ++q8) {
                int q = wv * 4 + q8;
                int row = q * 8 + (ln >> 3);
                int jj = (ln & 7) ^ (row & 7);
                gload_lds16((const char*)WoT + ((size_t)(cb + row)) * 512 + (size_t)kt * 128 + jj * 16,
                            (char*)wx + q * 1024);
            }
            __syncthreads();
#pragma unroll
            for (int ks = 0; ks < 2; ++ks) {
                bf16x8 xa[4], yb;
#pragma unroll
                for (int i = 0; i < 4; i++) {
                    int m = mg * 64 + i * 16 + (ln & 15);
                    int ch = (ks * 4 + (ln >> 4)) ^ (m & 7);
                    xa[i] = *(const bf16x8*)((const char*)wx + m * 128 + ch * 16);
                }
                {
                    int nr = nh * 16 + (ln & 15);
                    int cj = kt * 8 + ks * 4 + (ln >> 4);
                    yb = *(const bf16x8*)(sampL + nr * 512 + ((cj ^ (nr & 7)) * 16));
                }
#pragma unroll
                for (int i = 0; i < 4; i++)
                    acc[i] = __builtin_amdgcn_mfma_f32_16x16x32_bf16(xa[i], yb, acc[i], 0, 0, 0);
            }
            __syncthreads();
        }
        // epilogue: two 64-c' sub-halves through f32 tile [64][36]
#pragma unroll
        for (int hp = 0; hp < 2; ++hp) {
            if (mg == hp) {
#pragma unroll
                for (int i = 0; i < 4; i++) {
                    int c = nh * 16 + (ln & 15);
#pragma unroll
                    for (int rg = 0; rg < 4; rg++) {
                        int r = i * 16 + (ln >> 4) * 4 + rg;
                        tile[r * 36 + c] = acc[i][rg] + bout[cb + hp * 64 + r];
                    }
                }
            }
            __syncthreads();
            int g4 = (tid & 7) * 4;
            int rowbase = tid >> 3;           // 0..31
#pragma unroll
            for (int jj = 0; jj < 2; ++jj) {
                int r = rowbase + jj * 32;
                int crow = cb + hp * 64 + r;
                size_t off = (size_t)crow * NQ + nloc + g4;
                f32x4 tv = *(const f32x4*)&tile[r * 36 + g4];
                f32x4 qv = *(const f32x4*)(qp + off);
                f32x4 vv = *(const f32x4*)(vvp + off);
                float d = __expf((float)(2 * (crow >> 2)) * -PE_NEG);
                bool useY = (crow & 2) != 0, odd = (crow & 1) != 0;
                f32x4 pv;
#pragma unroll
                for (int e = 0; e < 4; ++e) {
                    int n = nloc + g4 + e;
                    int hh = n / WW, ww = n - hh * WW;
                    float pos = useY ? (float)(hh + 1) : (float)(ww + 1);
                    float sv, cv;
                    __sincosf(pos * d, &sv, &cv);
                    pv[e] = odd ? cv : sv;
                }
                f32x4 o1v = tv + qv + pv;
                *(f32x4*)(o1p + off) = o1v;
                *(f32x4*)(o0p + off) = o1v + vv;
            }
            __syncthreads();
        }
    }
}

extern "C" void kernel_launch(void* const* d_in, const int* in_sizes, int n_in,
                              void* d_out, int out_size, void* d_ws, size_t ws_size,
                              hipStream_t stream) {
    const float* query   = (const float*)d_in[0];
    const float* value   = (const float*)d_in[1];
    const float* W_value = (const float*)d_in[2];
    const float* b_value = (const float*)d_in[3];
    const float* W_off   = (const float*)d_in[4];
    const float* b_off   = (const float*)d_in[5];
    const float* W_attn  = (const float*)d_in[6];
    const float* b_attn  = (const float*)d_in[7];
    const float* W_out   = (const float*)d_in[8];
    const float* b_out   = (const float*)d_in[9];
    float* out = (float*)d_out;
    char* ws = (char*)d_ws;

    bf16_t* WvT   = (bf16_t*)(ws + 0);             //    131,072
    bf16_t* WoT   = (bf16_t*)(ws + 131072);        //    131,072
    bf16_t* WoaT  = (bf16_t*)(ws + 262144);        //     49,152
    bf16_t* vprojB= (bf16_t*)(ws + 311296);        // 26,214,400  (total ~26.5 MB)

    wprep_kernel<<<256, 256, 0, stream>>>(W_value, W_off, W_attn, W_out, WvT, WoaT, WoT);
    gemm_vproj<<<dim3(400, 2), 256, 0, stream>>>(value, WvT, b_value, vprojB);
    oa_sample_out<<<1600, 256, 0, stream>>>(query, WoaT, b_off, b_attn, vprojB,
                                            WoT, b_out, value, out);
}

// Round 13
// 101.800 us; speedup vs baseline: 2.0163x; 2.0163x over previous
//
#include <hip/hip_runtime.h>
#include <hip/hip_bf16.h>
#include <stdint.h>

#define HH 80
#define WW 80
#define NQ 6400        // H*W
#define CD 256         // embed dim
#define BB 8
#define OUT_HALF 13107200   // B*C*H*W
#define PE_NEG 0.0719557841560639f   // ln(10000)/128

typedef __attribute__((ext_vector_type(4))) float f32x4;
typedef __bf16 bf16_t;
typedef __attribute__((ext_vector_type(8))) __bf16 bf16x8;

using gp1_t = const __attribute__((address_space(1))) void*;
using lp3_t = __attribute__((address_space(3))) void*;

__device__ __forceinline__ void gload_lds16(const void* g, void* l) {
    __builtin_amdgcn_global_load_lds((gp1_t)g, (lp3_t)l, 16, 0, 0);
}

// ---------------- weight transposes -> bf16, rows = output col, K-contig ----------------
__global__ __launch_bounds__(256) void wprep_kernel(const float* __restrict__ Wv,
                                                    const float* __restrict__ Woff,
                                                    const float* __restrict__ Wattn,
                                                    const float* __restrict__ Wout,
                                                    bf16_t* __restrict__ WvT,
                                                    bf16_t* __restrict__ WoaT,
                                                    bf16_t* __restrict__ WoT) {
    int idx = blockIdx.x * 256 + threadIdx.x;
    if (idx < 65536) {
        int cp = idx >> 8, c = idx & 255;
        WvT[idx] = (bf16_t)Wv[c * 256 + cp];
        WoT[idx] = (bf16_t)Wout[c * 256 + cp];
    }
    if (idx < 96 * 256) {
        int j = idx >> 8, c = idx & 255;
        WoaT[idx] = (bf16_t)(j < 64 ? Woff[c * 64 + j] : Wattn[c * 32 + (j - 64)]);
    }
}

// ---- GEMM1: vproj[n][c'] = (value^T)[n][:] . WvT[c'][:] + b_value[c']  (bf16 out) ----
__global__ __launch_bounds__(256, 3) void gemm_vproj(const float* __restrict__ V,   // [b][c][n] f32
                                                     const bf16_t* __restrict__ Y,  // WvT [c'][c]
                                                     const float* __restrict__ bias,
                                                     bf16_t* __restrict__ D) {
    __shared__ __align__(16) bf16_t lx[128 * 72];   // [n][k] stride 72 elems = 144 B
    __shared__ __align__(16) bf16_t ly[128 * 64];
    int b = blockIdx.x & 7;
    int nloc = (blockIdx.x >> 3) * 128;
    int m0 = b * NQ + nloc;
    int c0 = blockIdx.y * 128;
    const float* src = V + (size_t)b * CD * NQ + nloc;
    int tid = threadIdx.x, wv = tid >> 6, ln = tid & 63;
    f32x4 acc[4][4] = {};
    int wr = (wv >> 1) * 64, wc = (wv & 1) * 64;
    int nl = tid & 31;
    for (int kt = 0; kt < 4; ++kt) {
#pragma unroll
        for (int q8 = 0; q8 < 4; ++q8) {
            int q = wv * 4 + q8;
            int row = q * 8 + (ln >> 3);
            int jj = (ln & 7) ^ (row & 7);
            gload_lds16((const char*)Y + ((size_t)(c0 + row)) * 512 + (size_t)kt * 128 + jj * 16,
                        (char*)ly + q * 1024);
        }
#pragma unroll
        for (int i = 0; i < 4; ++i) {
            int kp = (tid >> 5) + i * 8;
            int k = kp * 2;
            const float* s0 = src + (size_t)(kt * 64 + k) * NQ;
#pragma unroll
            for (int l = 0; l < 4; ++l) {
                int n = nl + 32 * l;
                float v0 = s0[n];
                float v1 = s0[NQ + n];
                union { bf16_t h[2]; uint32_t u; } pk;
                pk.h[0] = (bf16_t)v0; pk.h[1] = (bf16_t)v1;
                *(uint32_t*)((char*)lx + n * 144 + k * 2) = pk.u;
            }
        }
        __syncthreads();
#pragma unroll
        for (int ks = 0; ks < 2; ++ks) {
            bf16x8 xa[4], yb[4];
#pragma unroll
            for (int i = 0; i < 4; i++) {
                int m = wr + i * 16 + (ln & 15);
                xa[i] = *(const bf16x8*)((const char*)lx + m * 144 + ks * 64 + (ln >> 4) * 16);
                int n = wc + i * 16 + (ln & 15);
                int cn = (ks * 4 + (ln >> 4)) ^ (n & 7);
                yb[i] = *(const bf16x8*)((const char*)ly + n * 128 + cn * 16);
            }
#pragma unroll
            for (int i = 0; i < 4; i++)
#pragma unroll
                for (int j = 0; j < 4; j++)
                    acc[i][j] = __builtin_amdgcn_mfma_f32_16x16x32_bf16(xa[i], yb[j], acc[i][j], 0, 0, 0);
        }
        __syncthreads();
    }
#pragma unroll
    for (int i = 0; i < 4; i++)
#pragma unroll
        for (int j = 0; j < 4; j++) {
            int col = c0 + wc + j * 16 + (ln & 15);
            float bv = bias[col];
#pragma unroll
            for (int rg = 0; rg < 4; rg++) {
                int row = m0 + wr + i * 16 + (ln >> 4) * 4 + rg;
                D[(size_t)row * 256 + col] = (bf16_t)(acc[i][j][rg] + bv);
            }
        }
}

// ==== FUSED: oa GEMM + sampling (samp in LDS) + out GEMM (4 full-K passes) ====
// grid 800 = 8 batches (bid&7) x 100 tiles of 64 queries. 256 thr, 2 blocks/CU.
// LDS map: [0,32768)      samp 64x512B chunk-XOR-swizzled
//          [32768,65536)  phase A: lx[64][72]+ly[96][64]; phase C: wx[64][256] / tile[64][68]f32
//          [65536,78336)  oaT [64][100] bf16 (own region; lets pass-0 WoT stage overlap phase B)
__global__ __launch_bounds__(256, 2) void oa_sample_out(
        const float* __restrict__ Q,     // [b][c][n] f32
        const bf16_t* __restrict__ Woa,  // WoaT [j][c]
        const float* __restrict__ boff,
        const float* __restrict__ battn,
        const bf16_t* __restrict__ vp,   // vproj [b*NQ][256]
        const bf16_t* __restrict__ WoT,  // [c'][c]
        const float* __restrict__ bout,
        const float* __restrict__ value, // [b][c][n] f32
        float* __restrict__ out) {
    __shared__ __align__(16) char smem[78336];
    char* sampL = smem;                       // 32 KB
    bf16_t* lx = (bf16_t*)(smem + 32768);     // [64][72] (phase A)
    bf16_t* ly = (bf16_t*)(smem + 41984);     // [96][64] (phase A)
    char* wx = smem + 32768;                  // [64 c'][512 B] (phase C, XOR-swizzled)
    float* tile = (float*)(smem + 32768);     // [64][68] f32 (phase C epilogue)
    bf16_t* oaT = (bf16_t*)(smem + 65536);    // [64][100]

    int bid = blockIdx.x;
    int b = bid & 7;
    int nloc = (bid >> 3) * 64;               // query base within batch
    int tid = threadIdx.x, wv = tid >> 6, ln = tid & 63;
    const float* src = Q + (size_t)b * CD * NQ + nloc;
    int nl = tid & 31;

    // ---------------- Phase A: oa GEMM (M=64, N=96, K=256) ----------------
    f32x4 accA[6] = {};
    for (int kt = 0; kt < 4; ++kt) {
#pragma unroll
        for (int q3 = 0; q3 < 3; ++q3) {
            int q = wv * 3 + q3;
            int row = q * 8 + (ln >> 3);
            int jj = (ln & 7) ^ (row & 7);
            gload_lds16((const char*)Woa + ((size_t)row) * 512 + (size_t)kt * 128 + jj * 16,
                        (char*)ly + q * 1024);
        }
        // A stage with inline PE (64 rows)
#pragma unroll
        for (int i = 0; i < 4; ++i) {
            int kp = (tid >> 5) + i * 8;
            int k = kp * 2;
            int c = kt * 64 + k;
            float d = __expf((float)(2 * (c >> 2)) * -PE_NEG);
            const float* s0 = src + (size_t)c * NQ;
#pragma unroll
            for (int l = 0; l < 2; ++l) {
                int n = nl + 32 * l;
                int p = nloc + n;
                int h = p / WW, w = p - h * WW;
                float pos = (c & 2) ? (float)(h + 1) : (float)(w + 1);
                float sv, cv;
                __sincosf(pos * d, &sv, &cv);
                float v0 = s0[n] + sv;
                float v1 = s0[NQ + n] + cv;
                union { bf16_t hh[2]; uint32_t u; } pk;
                pk.hh[0] = (bf16_t)v0; pk.hh[1] = (bf16_t)v1;
                *(uint32_t*)((char*)lx + n * 144 + k * 2) = pk.u;
            }
        }
        __syncthreads();
#pragma unroll
        for (int ks = 0; ks < 2; ++ks) {
            bf16x8 xa, yb[6];
            int m = wv * 16 + (ln & 15);
            xa = *(const bf16x8*)((const char*)lx + m * 144 + ks * 64 + (ln >> 4) * 16);
#pragma unroll
            for (int j = 0; j < 6; j++) {
                int n = j * 16 + (ln & 15);
                int cn = (ks * 4 + (ln >> 4)) ^ (n & 7);
                yb[j] = *(const bf16x8*)((const char*)ly + n * 128 + cn * 16);
            }
#pragma unroll
            for (int j = 0; j < 6; j++)
                accA[j] = __builtin_amdgcn_mfma_f32_16x16x32_bf16(xa, yb[j], accA[j], 0, 0, 0);
        }
        __syncthreads();
    }
    // phase A epilogue -> oaT (own region, no alias with lx/ly)
#pragma unroll
    for (int j = 0; j < 6; j++) {
        int col = j * 16 + (ln & 15);
        float bv = col < 64 ? boff[col] : battn[col - 64];
#pragma unroll
        for (int rg = 0; rg < 4; rg++) {
            int rloc = wv * 16 + (ln >> 4) * 4 + rg;
            oaT[rloc * 100 + col] = (bf16_t)(accA[j][rg] + bv);
        }
    }
    __syncthreads();

    // Issue pass-0 WoT stage NOW (wx region dead; overlaps phase B's gather latency).
    // wx layout: [64 rows][32 chunks of 16B], LDS[r][j] = WoT[p*64+r][chunk j^(r&7)].
#pragma unroll
    for (int i = 0; i < 8; ++i) {
        int rr = (wv * 8 + i) * 2 + (ln >> 5);
        int jj = (ln & 31) ^ (rr & 7);
        gload_lds16((const char*)WoT + ((size_t)rr) * 512 + jj * 16,
                    wx + (wv * 8 + i) * 1024);
    }

    // ---------------- Phase B: sampling -> samp LDS (XOR-swizzled) ----------------
    {
        int h = (tid >> 1) & 7, sh = tid & 1;
        const bf16_t* vb = vp + (size_t)b * NQ * CD + h * 32 + sh * 16;
#pragma unroll
        for (int rnd = 0; rnd < 4; ++rnd) {
            int q = rnd * 16 + (tid >> 4);
            int n = nloc + q;
            const bf16_t* sq = oaT + q * 100;
            float l0 = (float)sq[64 + h * 4 + 0], l1 = (float)sq[64 + h * 4 + 1];
            float l2 = (float)sq[64 + h * 4 + 2], l3 = (float)sq[64 + h * 4 + 3];
            float mx = fmaxf(fmaxf(l0, l1), fmaxf(l2, l3));
            float e0 = __expf(l0 - mx), e1 = __expf(l1 - mx), e2 = __expf(l2 - mx), e3 = __expf(l3 - mx);
            float inv = 1.f / (e0 + e1 + e2 + e3);
            float aw[4] = {e0 * inv, e1 * inv, e2 * inv, e3 * inv};
            float xb = (float)(n % WW) * (80.f / 79.f) - 0.5f;
            float yb = (float)(n / WW) * (80.f / 79.f) - 0.5f;
            float wgt[16];
            int idx[16];
#pragma unroll
            for (int p = 0; p < 4; p++) {
                float x = xb + (float)sq[h * 8 + p * 2];
                float y = yb + (float)sq[h * 8 + p * 2 + 1];
                float x0f = floorf(x), y0f = floorf(y);
                float wx_ = x - x0f, wy_ = y - y0f;
                int ix = (int)x0f, iy = (int)y0f;
                bool vx0 = (unsigned)ix < (unsigned)WW, vx1 = (unsigned)(ix + 1) < (unsigned)WW;
                bool vy0 = (unsigned)iy < (unsigned)HH, vy1 = (unsigned)(iy + 1) < (unsigned)HH;
                int cx0 = min(max(ix, 0), WW - 1), cx1 = min(max(ix + 1, 0), WW - 1);
                int cy0 = min(max(iy, 0), HH - 1), cy1 = min(max(iy + 1, 0), HH - 1);
                float ap = aw[p];
                wgt[p * 4 + 0] = (vx0 && vy0) ? ap * (1.f - wx_) * (1.f - wy_) : 0.f;
                wgt[p * 4 + 1] = (vx1 && vy0) ? ap * wx_ * (1.f - wy_) : 0.f;
                wgt[p * 4 + 2] = (vx0 && vy1) ? ap * (1.f - wx_) * wy_ : 0.f;
                wgt[p * 4 + 3] = (vx1 && vy1) ? ap * wx_ * wy_ : 0.f;
                idx[p * 4 + 0] = cy0 * WW + cx0;
                idx[p * 4 + 1] = cy0 * WW + cx1;
                idx[p * 4 + 2] = cy1 * WW + cx0;
                idx[p * 4 + 3] = cy1 * WW + cx1;
            }
            float fac[16];
#pragma unroll
            for (int j = 0; j < 16; j++) fac[j] = 0.f;
#pragma unroll
            for (int pc = 0; pc < 16; ++pc) {
                const bf16x8* p8 = (const bf16x8*)(vb + (size_t)idx[pc] * CD);
                bf16x8 v0 = p8[0], v1 = p8[1];
                float w = wgt[pc];
#pragma unroll
                for (int j = 0; j < 8; j++) fac[j] += (float)v0[j] * w;
#pragma unroll
                for (int j = 0; j < 8; j++) fac[8 + j] += (float)v1[j] * w;
            }
            bf16x8 o0, o1;
#pragma unroll
            for (int j = 0; j < 8; j++) { o0[j] = (bf16_t)fac[j]; o1[j] = (bf16_t)fac[8 + j]; }
            int c0 = 4 * h + 2 * sh;          // 16B chunk index (of 32)
            *(bf16x8*)(sampL + q * 512 + ((c0 ^ (q & 7)) * 16)) = o0;
            *(bf16x8*)(sampL + q * 512 + (((c0 + 1) ^ (q & 7)) * 16)) = o1;
        }
    }
    __syncthreads();   // drains vmcnt -> pass-0 stage landed; sampL visible

    // ---------------- Phase C: out GEMM 256c' x 64n, 4 passes of 64 c' (full-K stage) ----------------
    const float* qp = Q + (size_t)b * CD * NQ;
    const float* vvp = value + (size_t)b * CD * NQ;
    float* o0p = out + (size_t)b * CD * NQ;
    float* o1p = out + OUT_HALF + (size_t)b * CD * NQ;
    for (int p = 0; p < 4; ++p) {
        f32x4 acc[4] = {};
        int m = wv * 16 + (ln & 15);
#pragma unroll
        for (int ks2 = 0; ks2 < 8; ++ks2) {   // 8 k-slices, no barriers
            bf16x8 xa, yb[4];
            int kc = ks2 * 4 + (ln >> 4);
            xa = *(const bf16x8*)(wx + m * 512 + ((kc ^ (m & 7)) * 16));
#pragma unroll
            for (int j = 0; j < 4; j++) {
                int nr = j * 16 + (ln & 15);
                yb[j] = *(const bf16x8*)(sampL + nr * 512 + ((kc ^ (nr & 7)) * 16));
            }
#pragma unroll
            for (int j = 0; j < 4; j++)
                acc[j] = __builtin_amdgcn_mfma_f32_16x16x32_bf16(xa, yb[j], acc[j], 0, 0, 0);
        }
        __syncthreads();           // all wx reads done -> safe to overwrite with tile
#pragma unroll
        for (int j = 0; j < 4; j++) {
            int c = j * 16 + (ln & 15);
#pragma unroll
            for (int rg = 0; rg < 4; rg++) {
                int r = wv * 16 + (ln >> 4) * 4 + rg;
                tile[r * 68 + c] = acc[j][rg] + bout[p * 64 + r];
            }
        }
        __syncthreads();
        int g4 = (tid & 15) * 4;
        int rowbase = tid >> 4;
#pragma unroll
        for (int jj2 = 0; jj2 < 4; ++jj2) {
            int r = rowbase + jj2 * 16;
            int crow = p * 64 + r;
            size_t off = (size_t)crow * NQ + nloc + g4;
            f32x4 tv = *(const f32x4*)&tile[r * 68 + g4];
            f32x4 qv = *(const f32x4*)(qp + off);
            f32x4 vv = *(const f32x4*)(vvp + off);
            float d = __expf((float)(2 * (crow >> 2)) * -PE_NEG);
            bool useY = (crow & 2) != 0, odd = (crow & 1) != 0;
            f32x4 pv;
#pragma unroll
            for (int e = 0; e < 4; ++e) {
                int n = nloc + g4 + e;
                int hh = n / WW, ww = n - hh * WW;
                float pos = useY ? (float)(hh + 1) : (float)(ww + 1);
                float sv, cv;
                __sincosf(pos * d, &sv, &cv);
                pv[e] = odd ? cv : sv;
            }
            f32x4 o1v = tv + qv + pv;
            *(f32x4*)(o1p + off) = o1v;
            *(f32x4*)(o0p + off) = o1v + vv;
        }
        __syncthreads();           // tile reads done
        if (p < 3) {
            // stage next pass's 64 c' x 256 k (32 KB)
#pragma unroll
            for (int i = 0; i < 8; ++i) {
                int rr = (wv * 8 + i) * 2 + (ln >> 5);
                int jj = (ln & 31) ^ (rr & 7);
                gload_lds16((const char*)WoT + ((size_t)((p + 1) * 64 + rr)) * 512 + jj * 16,
                            wx + (wv * 8 + i) * 1024);
            }
            __syncthreads();       // stage landed
        }
    }
}

extern "C" void kernel_launch(void* const* d_in, const int* in_sizes, int n_in,
                              void* d_out, int out_size, void* d_ws, size_t ws_size,
                              hipStream_t stream) {
    const float* query   = (const float*)d_in[0];
    const float* value   = (const float*)d_in[1];
    const float* W_value = (const float*)d_in[2];
    const float* b_value = (const float*)d_in[3];
    const float* W_off   = (const float*)d_in[4];
    const float* b_off   = (const float*)d_in[5];
    const float* W_attn  = (const float*)d_in[6];
    const float* b_attn  = (const float*)d_in[7];
    const float* W_out   = (const float*)d_in[8];
    const float* b_out   = (const float*)d_in[9];
    float* out = (float*)d_out;
    char* ws = (char*)d_ws;

    bf16_t* WvT   = (bf16_t*)(ws + 0);             //    131,072
    bf16_t* WoT   = (bf16_t*)(ws + 131072);        //    131,072
    bf16_t* WoaT  = (bf16_t*)(ws + 262144);        //     49,152
    bf16_t* vprojB= (bf16_t*)(ws + 311296);        // 26,214,400  (total ~26.5 MB)

    wprep_kernel<<<256, 256, 0, stream>>>(W_value, W_off, W_attn, W_out, WvT, WoaT, WoT);
    gemm_vproj<<<dim3(400, 2), 256, 0, stream>>>(value, WvT, b_value, vprojB);
    oa_sample_out<<<800, 256, 0, stream>>>(query, WoaT, b_off, b_attn, vprojB,
                                           WoT, b_out, value, out);
}